// Round 16
// baseline (149.500 us; speedup 1.0000x reference)
//
#include <hip/hip_runtime.h>

// GCN layer: out = A_sparse @ (X @ W) + bias
// R16: exploit linearity A@(X@W) = (A@X)@W. Aggregate edges in X-space
// (random-gather cost identical: X16 is 12.8MB bf16 like S16 was), then apply
// W via MFMA inside the same per-bucket kernel. Deletes the standalone GEMM
// stage, the S16 round-trip, and one launch. pass1 + gather mechanics = R12.

#define N_NODES 50000
#define N_EDGES 800000
#define D 128
#define BROWS 66               // rows per bucket
#define NBUCKET 758            // ceil(50000/66)
#define SLOT 1536              // per-bucket capacity (mean 1052, +15 sigma)
#define CHUNK 2048             // edges per pass1 block
#define EPT 8                  // CHUNK/256
#define XCONV_BLOCKS 782       // X->bf16: 782*2048 float4 >= 1.6M
#define PASS1_BLOCKS 391       // ceil(800000/2048)
#define CSTRIDE 16             // gcursor padding: 16 ints = 64B per cursor

typedef short bf16x8 __attribute__((ext_vector_type(8)));
typedef float f32x4 __attribute__((ext_vector_type(4)));

__device__ inline unsigned short f2bf(float f) {   // RNE f32 -> bf16 bits
    unsigned u = __float_as_uint(f);
    unsigned r = (u + 0x7FFFu + ((u >> 16) & 1u)) >> 16;
    return (unsigned short)r;
}

// ---- ws layout (bytes) ----
// X16:      [0, 12800000)            bf16 X [50000][128]
// staging:  [12800000, +9314304)     758*1536 int2 (lrow<<16|col, bits(w))
// gcursor:  [22114304, +48512)       758 cursors, 64B apart
// WT16:     [22162816, +34816)       bf16 W^T padded [128][136]

// ---------------- K0: W^T bf16 prep + cursor zero (once) ----------------
__global__ __launch_bounds__(256) void wprep_kernel(const float* __restrict__ W,
                                                    unsigned short* __restrict__ WT,
                                                    int* __restrict__ gcursor) {
    int idx = blockIdx.x * 256 + threadIdx.x;
    if (idx < 128 * 128) {
        int k = idx >> 7, n = idx & 127;
        WT[n * 136 + k] = f2bf(W[idx]);
    }
    if (idx < NBUCKET * CSTRIDE) gcursor[idx] = 0;
}

// ---------------- K1: prep = X->bf16 convert (blocks < XCONV) || pass1 -----
__global__ __launch_bounds__(256) void prep_kernel(const float* __restrict__ X,
                                                   unsigned short* __restrict__ X16,
                                                   const int* __restrict__ ei,
                                                   const float* __restrict__ ew,
                                                   int* __restrict__ gcursor,
                                                   int2* __restrict__ staging) {
    __shared__ __align__(16) char shmem[29712];
    const int t = threadIdx.x;
    const int lane = t & 63, wid = t >> 6;

    if (blockIdx.x < XCONV_BLOCKS) {
        // ================= X -> bf16 (coalesced, no reuse) =================
        const float4* X4 = (const float4*)X;
#pragma unroll
        for (int i = 0; i < 8; ++i) {
            int idx4 = blockIdx.x * 2048 + t + 256 * i;
            if (idx4 < N_NODES * 32) {
                float4 v = X4[idx4];
                ((ushort4*)X16)[idx4] =
                    make_ushort4(f2bf(v.x), f2bf(v.y), f2bf(v.z), f2bf(v.w));
            }
        }
    } else {
        // ================= PASS1: bucket multisplit (758 buckets) =========
        int* bufx            = (int*)shmem;                         // [2048] 8KB
        int* bufw            = (int*)(shmem + 8192);                // [2048] 8KB
        unsigned short* bof  = (unsigned short*)(shmem + 16384);    // [2048] 4KB
        int* hist            = (int*)(shmem + 20480);               // [768]
        int* lcur            = (int*)(shmem + 23552);               // [768]
        int* bmg             = (int*)(shmem + 26624);               // [768]
        int* wsum            = (int*)(shmem + 29696);               // [4]
        const int base = (blockIdx.x - XCONV_BLOCKS) * CHUNK;

        hist[t] = 0;
        hist[t + 256] = 0;
        hist[t + 512] = 0;
        __syncthreads();

        int rows[EPT];
        int bkt[EPT];
#pragma unroll
        for (int i = 0; i < EPT; ++i) {
            int e = base + t + 256 * i;
            rows[i] = (e < N_EDGES) ? ei[e] : -1;
            bkt[i] = (rows[i] >= 0) ? (rows[i] / BROWS) : -1;
            if (bkt[i] >= 0) atomicAdd(&hist[bkt[i]], 1);
        }
        __syncthreads();

        // three-phase wave-shfl exclusive scan of hist[768]
        int run = 0, exv[3], vv[3];
#pragma unroll
        for (int ph = 0; ph < 3; ++ph) {
            int v = hist[ph * 256 + t];
            vv[ph] = v;
            int incl = v;
#pragma unroll
            for (int off = 1; off < 64; off <<= 1) {
                int x = __shfl_up(incl, off, 64);
                if (lane >= off) incl += x;
            }
            if (lane == 63) wsum[wid] = incl;
            __syncthreads();
            int pre = 0, tot = 0;
#pragma unroll
            for (int w = 0; w < 4; ++w) {
                int x = wsum[w];
                if (w < wid) pre += x;
                tot += x;
            }
            exv[ph] = run + incl - v + pre;
            run += tot;
            __syncthreads();
        }
        const int total = run;
        lcur[t] = exv[0];
        lcur[t + 256] = exv[1];
        lcur[t + 512] = exv[2];
#pragma unroll
        for (int ph = 0; ph < 3; ++ph) {
            int b = ph * 256 + t;
            if (b < NBUCKET) {
                int v = vv[ph];
                if (v > 0) {
                    int gb = atomicAdd(&gcursor[b * CSTRIDE], v);
                    bmg[b] = b * SLOT + gb - exv[ph];
                }
            }
        }
        __syncthreads();

        // local reorder into bucket-contiguous LDS (SoA: 4B writes)
#pragma unroll
        for (int i = 0; i < EPT; ++i) {
            if (rows[i] >= 0) {
                int e = base + t + 256 * i;
                int col = ei[N_EDGES + e];
                float w = ew[e];
                int b = bkt[i];
                int lp = atomicAdd(&lcur[b], 1);
                int lrow = rows[i] - b * BROWS;     // 0..65
                bufx[lp] = (int)(((unsigned)lrow << 16) | (unsigned)col);
                bufw[lp] = __float_as_int(w);
                bof[lp] = (unsigned short)b;
            }
        }
        __syncthreads();

        // coalesced sweep: consecutive lp in same bucket -> consecutive gaddr
        for (int lp = t; lp < total; lp += 256) {
            int b = bof[lp];
            int g = bmg[b] + lp;
            if (g < (b + 1) * SLOT)
                staging[g] = make_int2(bufx[lp], bufw[lp]);   // overflow guard
        }
    }
}

// ---------------- K2: mega = sort + X-space aggregate + MFMA @W ------------
// One 512-thread block per 66-row bucket.
// A: hist (global staging read), scan, sort into in1 (LDS).
// B: aggregate Y[row] = sum w*X16[col] (8 subs x 8 lanes, reg acc, shfl
//    reduce) -> bf16 into yt [80][136] LDS tile (rows 66..79 zeroed).
// C: out_tile = yt @ W via MFMA (B-frags from global WT16, L2-hot), +bias,
//    direct f32 stores (16-lane row segments = 64B).
__global__ __launch_bounds__(512) void mega_kernel(const unsigned short* __restrict__ X16,
                                                   const int* __restrict__ gcursor,
                                                   const int2* __restrict__ staging,
                                                   const unsigned short* __restrict__ WT,
                                                   const float* __restrict__ bias,
                                                   float* __restrict__ out) {
    __shared__ int2 in1[SLOT];                 // 12288 B
    __shared__ unsigned short yt[80 * 136];    // 21760 B
    __shared__ int hist[128];
    __shared__ int exs[128];
    __shared__ int lcur[128];
    __shared__ int wsum[2];
    const int t = threadIdx.x;
    const int b = blockIdx.x;
    const int lane = t & 63;
    int cnt = gcursor[b * CSTRIDE];
    if (cnt > SLOT) cnt = SLOT;

    if (t < 128) hist[t] = 0;
    // zero pad rows 66..79 of yt (14*136 ushorts = 952 uints)
    for (int i = t; i < 952; i += 512) ((unsigned*)&yt[66 * 136])[i] = 0u;
    __syncthreads();

    for (int i = t; i < cnt; i += 512)
        atomicAdd(&hist[((unsigned)staging[b * SLOT + i].x >> 16) & 127u], 1);
    __syncthreads();

    // scan hist[128] on threads 0..127
    int v = 0, incl = 0;
    if (t < 128) {
        v = hist[t];
        incl = v;
#pragma unroll
        for (int off = 1; off < 64; off <<= 1) {
            int x = __shfl_up(incl, off, 64);
            if (lane >= off) incl += x;
        }
        if (lane == 63) wsum[t >> 6] = incl;
    }
    __syncthreads();
    if (t < 128) {
        int pre = (t >= 64) ? wsum[0] : 0;
        int ex = incl - v + pre;
        exs[t] = ex;
        lcur[t] = ex;
    }
    __syncthreads();

    // sort payload into in1 (row-contiguous), re-reading staging (L2-warm)
    for (int i = t; i < cnt; i += 512) {
        int2 e = staging[b * SLOT + i];
        int lr = (int)(((unsigned)e.x >> 16) & 127u);
        int p = atomicAdd(&lcur[lr], 1);
        in1[p] = e;
    }
    __syncthreads();

    // ---- B: aggregate in X-space ----
    const int wv = t >> 6;                   // 0..7
    const int sub = lane >> 3;               // 0..7 edge sub-streams
    const int q = lane & 7;                  // owns dims q*16..q*16+15
    const uint4* S4 = (const uint4*)X16;     // row stride: 16 uint4

    for (int rr = wv; rr < BROWS; rr += 8) {
        int beg = exs[rr];
        int end = beg + hist[rr];
        float acc[16];
#pragma unroll
        for (int i = 0; i < 16; ++i) acc[i] = 0.f;
        for (int p = beg + sub; p < end; p += 8) {
            int2 cw = in1[p];                // broadcast across 8 lanes
            float w = __int_as_float(cw.y);
            int col = cw.x & 0xFFFF;
            uint4 v0 = S4[col * 16 + q * 2];
            uint4 v1 = S4[col * 16 + q * 2 + 1];
            acc[0]  += __uint_as_float(v0.x << 16) * w;
            acc[1]  += __uint_as_float(v0.x & 0xFFFF0000u) * w;
            acc[2]  += __uint_as_float(v0.y << 16) * w;
            acc[3]  += __uint_as_float(v0.y & 0xFFFF0000u) * w;
            acc[4]  += __uint_as_float(v0.z << 16) * w;
            acc[5]  += __uint_as_float(v0.z & 0xFFFF0000u) * w;
            acc[6]  += __uint_as_float(v0.w << 16) * w;
            acc[7]  += __uint_as_float(v0.w & 0xFFFF0000u) * w;
            acc[8]  += __uint_as_float(v1.x << 16) * w;
            acc[9]  += __uint_as_float(v1.x & 0xFFFF0000u) * w;
            acc[10] += __uint_as_float(v1.y << 16) * w;
            acc[11] += __uint_as_float(v1.y & 0xFFFF0000u) * w;
            acc[12] += __uint_as_float(v1.z << 16) * w;
            acc[13] += __uint_as_float(v1.z & 0xFFFF0000u) * w;
            acc[14] += __uint_as_float(v1.w << 16) * w;
            acc[15] += __uint_as_float(v1.w & 0xFFFF0000u) * w;
        }
#pragma unroll
        for (int i = 0; i < 16; ++i) acc[i] += __shfl_xor(acc[i], 8, 64);
#pragma unroll
        for (int i = 0; i < 16; ++i) acc[i] += __shfl_xor(acc[i], 16, 64);
#pragma unroll
        for (int i = 0; i < 16; ++i) acc[i] += __shfl_xor(acc[i], 32, 64);
        if (sub == 0) {
            ushort4 u0 = make_ushort4(f2bf(acc[0]),  f2bf(acc[1]),
                                      f2bf(acc[2]),  f2bf(acc[3]));
            ushort4 u1 = make_ushort4(f2bf(acc[4]),  f2bf(acc[5]),
                                      f2bf(acc[6]),  f2bf(acc[7]));
            ushort4 u2 = make_ushort4(f2bf(acc[8]),  f2bf(acc[9]),
                                      f2bf(acc[10]), f2bf(acc[11]));
            ushort4 u3 = make_ushort4(f2bf(acc[12]), f2bf(acc[13]),
                                      f2bf(acc[14]), f2bf(acc[15]));
            *(ushort4*)&yt[rr * 136 + q * 16]      = u0;
            *(ushort4*)&yt[rr * 136 + q * 16 + 4]  = u1;
            *(ushort4*)&yt[rr * 136 + q * 16 + 8]  = u2;
            *(ushort4*)&yt[rr * 136 + q * 16 + 12] = u3;
        }
    }
    __syncthreads();

    // ---- C: out = yt @ W + bias via MFMA ----
    // wave wv owns N-tile (cols wv*16..+15); 5 M-tiles cover rows 0..79.
    const int m = lane & 15;
    const int qq = lane >> 4;
    bf16x8 bfrag[4];
#pragma unroll
    for (int ks = 0; ks < 4; ++ks)
        bfrag[ks] = *(const bf16x8*)&WT[(wv * 16 + m) * 136 + ks * 32 + qq * 8];

    float bv = bias[wv * 16 + m];
    f32x4 cacc[5];
#pragma unroll
    for (int mt = 0; mt < 5; ++mt) cacc[mt] = (f32x4){0.f, 0.f, 0.f, 0.f};
#pragma unroll
    for (int mt = 0; mt < 5; ++mt) {
#pragma unroll
        for (int ks = 0; ks < 4; ++ks) {
            bf16x8 a = *(const bf16x8*)&yt[(mt * 16 + m) * 136 + ks * 32 + qq * 8];
            cacc[mt] = __builtin_amdgcn_mfma_f32_16x16x32_bf16(a, bfrag[ks], cacc[mt], 0, 0, 0);
        }
    }
    // C/D: col = wv*16+m, row = mt*16 + qq*4 + r
#pragma unroll
    for (int mt = 0; mt < 5; ++mt) {
#pragma unroll
        for (int r = 0; r < 4; ++r) {
            int row = mt * 16 + qq * 4 + r;
            int gr = b * BROWS + row;
            if (row < BROWS && gr < N_NODES)
                out[gr * 128 + wv * 16 + m] = cacc[mt][r] + bv;
        }
    }
}

extern "C" void kernel_launch(void* const* d_in, const int* in_sizes, int n_in,
                              void* d_out, int out_size, void* d_ws, size_t ws_size,
                              hipStream_t stream) {
    const float* X    = (const float*)d_in[0];
    const int*   ei   = (const int*)d_in[1];
    const float* ew   = (const float*)d_in[2];
    const float* W    = (const float*)d_in[3];
    const float* bias = (const float*)d_in[4];
    float* out = (float*)d_out;

    char* ws = (char*)d_ws;
    unsigned short* X16 = (unsigned short*)(ws);
    int2* staging = (int2*)(ws + 12800000);
    int*  gcursor = (int*)(ws + 22114304);
    unsigned short* WT16 = (unsigned short*)(ws + 22162816);

    wprep_kernel<<<64, 256, 0, stream>>>(W, WT16, gcursor);
    prep_kernel<<<XCONV_BLOCKS + PASS1_BLOCKS, 256, 0, stream>>>(X, X16, ei, ew,
                                                                 gcursor, staging);
    mega_kernel<<<NBUCKET, 512, 0, stream>>>(X16, gcursor, staging, WT16, bias, out);
}